// Round 1
// baseline (1306.488 us; speedup 1.0000x reference)
//
#include <hip/hip_runtime.h>
#include <math.h>

#define D 64
#define H 128
#define KIN 8
#define KOUT 4
#define NPB 16                 // nodes per block
#define ROWS (NPB*KOUT)        // 64 MLP rows per block
#define THREADS 256
#define WAVES 4
#define NPW (NPB/WAVES)        // 4 nodes per wave
#define XLD 132                // xbuf leading dim (128 + 4 pad, 16B aligned)
#define KT 32                  // weight k-tile
#define WLD 132
#define ELD 68                 // eins leading dim (64 + 4, 16B aligned, conflict-free)

__global__ __launch_bounds__(THREADS, 2) void encoder_kernel(
    const float* __restrict__ edges,
    const int*   __restrict__ in_idx,
    const int*   __restrict__ in_mask,
    const int*   __restrict__ out_idx,
    const int*   __restrict__ out_mask,
    const float* __restrict__ W0, const float* __restrict__ b0,
    const float* __restrict__ W1, const float* __restrict__ b1,
    const float* __restrict__ Wout, const float* __restrict__ bout,
    float* __restrict__ out, int N)
{
    __shared__ float xbuf[ROWS][XLD];      // 64*132*4 = 33792 B
    __shared__ float wbuf[KT][WLD];        // 32*132*4 = 16896 B
    __shared__ float eins[WAVES][KIN][ELD];// 4*8*68*4 =  8704 B
    __shared__ float omaskf[ROWS];         //              256 B   => ~58 KB total

    const int tid  = threadIdx.x;
    const int wave = tid >> 6;
    const int lane = tid & 63;
    const int nodeBase = blockIdx.x * NPB;

    // ---------------- Phase 1: attention + pooling + gathers ----------------
    const int q   = lane >> 3;   // query row for score lane
    const int kk8 = lane & 7;    // key row for score lane
    for (int it = 0; it < NPW; ++it) {
        const int nl = wave * NPW + it;      // local node 0..15
        const int n  = nodeBase + nl;
        __syncthreads();                     // protect eins overwrite (uniform loop)
        if (n < N) {
            // gather 8 in-edges, one row per e, lane = feature d (coalesced 256B)
            #pragma unroll
            for (int e = 0; e < KIN; ++e) {
                const int idx = in_idx[n*KIN + e];
                eins[wave][e][lane] = edges[(size_t)idx * D + lane];
            }
        }
        __syncthreads();                     // eins visible to whole wave
        if (n < N) {
            float denom = 0.f;
            #pragma unroll
            for (int e = 0; e < KIN; ++e) denom += (float)in_mask[n*KIN + e];
            denom = fmaxf(denom, 1.f);
            const float mk_k = (float)in_mask[n*KIN + kk8];  // key mask (this lane)
            const float mk_q = (float)in_mask[n*KIN + q];    // query mask (this lane)

            // score[q][kk8] = (Ein[q]·Ein[kk8]) / sqrt(64)
            float s = 0.f;
            #pragma unroll
            for (int d4 = 0; d4 < D; d4 += 4) {
                const float4 a = *(const float4*)&eins[wave][q][d4];
                const float4 b = *(const float4*)&eins[wave][kk8][d4];
                s += a.x*b.x + a.y*b.y + a.z*b.z + a.w*b.w;
            }
            s *= 0.125f;
            if (mk_k == 0.f) s = -1e9f;

            // softmax over k within each 8-lane group
            float mx = s;
            #pragma unroll
            for (int off = 1; off < 8; off <<= 1) mx = fmaxf(mx, __shfl_xor(mx, off));
            const float ex = __expf(s - mx);
            float sum = ex;
            #pragma unroll
            for (int off = 1; off < 8; off <<= 1) sum += __shfl_xor(sum, off);

            // w[k] = sum_q maskq * attn[q][k]   (query-mask-weighted column sums)
            float wk = mk_q * (ex / sum);
            #pragma unroll
            for (int off = 8; off < 64; off <<= 1) wk += __shfl_xor(wk, off);
            // every lane now holds w[k = lane&7]; lane j (j<8) holds w[j]

            // pooled[d=lane] = sum_k w[k]*Ein[k][d] / denom
            float p = 0.f;
            #pragma unroll
            for (int j = 0; j < KIN; ++j) p += __shfl(wk, j) * eins[wave][j][lane];
            p /= denom;

            // gather out-edges and assemble x = [Eout | pooled]
            #pragma unroll
            for (int j = 0; j < KOUT; ++j) {
                const int oi = out_idx[n*KOUT + j];
                xbuf[nl*KOUT + j][lane]     = edges[(size_t)oi * D + lane];
                xbuf[nl*KOUT + j][D + lane] = p;
            }
            if (lane < KOUT) omaskf[nl*KOUT + lane] = (float)out_mask[n*KOUT + lane];
        }
    }
    __syncthreads();

    // ---------------- Phase 2: two 64x128x128 fp32 GEMM layers ----------------
    const int tr = tid >> 5;   // 0..7  -> output rows tr*8 .. tr*8+7
    const int tc = tid & 31;   // 0..31 -> output cols tc*4 .. tc*4+3

    for (int layer = 0; layer < 2; ++layer) {
        const float* __restrict__ Wg = layer ? W1 : W0;
        const float* __restrict__ bg = layer ? b1 : b0;
        float acc[8][4];
        const float4 bb = *(const float4*)&bg[tc*4];
        #pragma unroll
        for (int i = 0; i < 8; ++i) { acc[i][0]=bb.x; acc[i][1]=bb.y; acc[i][2]=bb.z; acc[i][3]=bb.w; }

        for (int kt = 0; kt < H; kt += KT) {
            __syncthreads();   // previous tile fully consumed
            // stage W^T tile: wbuf[kk][h] = W[h][kt+kk]  (global reads coalesced per 128B)
            for (int t = tid; t < H*KT; t += THREADS) {
                const int h = t >> 5, kkk = t & 31;
                wbuf[kkk][h] = Wg[h*H + kt + kkk];
            }
            __syncthreads();
            #pragma unroll
            for (int kc = 0; kc < KT; kc += 4) {
                float4 xa[8];
                #pragma unroll
                for (int i = 0; i < 8; ++i) xa[i] = *(const float4*)&xbuf[tr*8+i][kt+kc];
                #pragma unroll
                for (int u = 0; u < 4; ++u) {
                    const float4 wv = *(const float4*)&wbuf[kc+u][tc*4]; // contiguous over h
                    #pragma unroll
                    for (int i = 0; i < 8; ++i) {
                        const float xv = (&xa[i].x)[u];
                        acc[i][0] += xv*wv.x; acc[i][1] += xv*wv.y;
                        acc[i][2] += xv*wv.z; acc[i][3] += xv*wv.w;
                    }
                }
            }
        }
        __syncthreads();   // all x reads done, safe to overwrite
        #pragma unroll
        for (int i = 0; i < 8; ++i) {
            float4 st;
            st.x = fmaxf(acc[i][0], 0.f); st.y = fmaxf(acc[i][1], 0.f);
            st.z = fmaxf(acc[i][2], 0.f); st.w = fmaxf(acc[i][3], 0.f);
            *(float4*)&xbuf[tr*8+i][tc*4] = st;
        }
        __syncthreads();
    }

    // ---------------- epilogue: y = h1 . Wout + bout, masked ----------------
    if (tid < ROWS) {
        const long long grow = (long long)nodeBase * KOUT + tid;
        if (grow < (long long)N * KOUT) {
            float y = bout[0];
            #pragma unroll
            for (int h4 = 0; h4 < H; h4 += 4) {
                const float4 xv = *(const float4*)&xbuf[tid][h4];
                const float4 wv = *(const float4*)&Wout[h4];
                y += xv.x*wv.x + xv.y*wv.y + xv.z*wv.z + xv.w*wv.w;
            }
            out[grow] = y * omaskf[tid];
        }
    }
}

extern "C" void kernel_launch(void* const* d_in, const int* in_sizes, int n_in,
                              void* d_out, int out_size, void* d_ws, size_t ws_size,
                              hipStream_t stream)
{
    const float* edges  = (const float*)d_in[0];
    const int* in_idx   = (const int*)d_in[1];
    const int* in_mask  = (const int*)d_in[2];
    const int* out_idx  = (const int*)d_in[3];
    const int* out_mask = (const int*)d_in[4];
    const float* W0   = (const float*)d_in[5];
    const float* b0   = (const float*)d_in[6];
    const float* W1   = (const float*)d_in[7];
    const float* b1   = (const float*)d_in[8];
    const float* Wout = (const float*)d_in[9];
    const float* bout = (const float*)d_in[10];
    float* out = (float*)d_out;

    const int nNodes = in_sizes[1] / KIN;              // 200000
    const int grid   = (nNodes + NPB - 1) / NPB;       // 12500
    encoder_kernel<<<grid, THREADS, 0, stream>>>(
        edges, in_idx, in_mask, out_idx, out_mask,
        W0, b0, W1, b1, Wout, bout, out, nNodes);
}

// Round 2
// 573.097 us; speedup vs baseline: 2.2797x; 2.2797x over previous
//
#include <hip/hip_runtime.h>
#include <math.h>

#define D 64
#define H 128
#define KIN 8
#define KOUT 4
#define NPB 16                 // nodes per block
#define ROWS (NPB*KOUT)        // 64 MLP rows per block
#define THREADS 256
#define WAVES 4
#define NPW (NPB/WAVES)        // 4 nodes per wave
#define XLDB 136               // xbuf leading dim in bf16 (136*2B=272B, %128B=16B -> 2-way reads, free)
#define ELD 68                 // eins leading dim fp32 (64+4)

typedef __attribute__((ext_vector_type(8))) short short8v;  // 8 bf16 = 4 VGPR
typedef __attribute__((ext_vector_type(4))) float f32x4;

__device__ inline unsigned short f2bf(float f) {            // RNE float->bf16
    union { float f; unsigned u; } v; v.f = f;
    unsigned r = v.u + 0x7FFF + ((v.u >> 16) & 1);
    return (unsigned short)(r >> 16);
}
__device__ inline float bf2f(unsigned short h) {
    union { unsigned u; float f; } v; v.u = ((unsigned)h) << 16; return v.f;
}

// ---- weight pre-conversion: W0,W1 (fp32, 128x128 each) -> bf16 in ws ----
__global__ void convert_w_kernel(const float* __restrict__ W0,
                                 const float* __restrict__ W1,
                                 unsigned short* __restrict__ Wbf) {
    const int i = blockIdx.x * 256 + threadIdx.x;           // 0 .. 32767
    const float v = (i < H*H) ? W0[i] : W1[i - H*H];
    Wbf[i] = f2bf(v);
}

__global__ __launch_bounds__(THREADS, 4) void encoder_kernel(
    const float* __restrict__ edges,
    const int*   __restrict__ in_idx,
    const int*   __restrict__ in_mask,
    const int*   __restrict__ out_idx,
    const int*   __restrict__ out_mask,
    const float* __restrict__ b0, const float* __restrict__ b1,
    const float* __restrict__ Wout, const float* __restrict__ bout,
    const unsigned short* __restrict__ Wbf,   // [2][128][128] bf16 (W0bf, W1bf)
    float* __restrict__ out, int N)
{
    __shared__ unsigned short xbuf[ROWS][XLDB];   // 17408 B (x / h, bf16)
    __shared__ float eins[WAVES][KIN][ELD];       //  8704 B
    __shared__ float omaskf[ROWS];                //   256 B   => ~26.4 KB

    const int tid  = threadIdx.x;
    const int wave = tid >> 6;
    const int lane = tid & 63;
    const int nodeBase = blockIdx.x * NPB;

    // ---------------- Phase 1: attention + pooling + gathers (per-wave, no barriers) ----
    const int q   = lane >> 3;
    const int kk8 = lane & 7;
    for (int it = 0; it < NPW; ++it) {
        const int nl = wave * NPW + it;
        const int n  = nodeBase + nl;
        if (n < N) {
            #pragma unroll
            for (int e = 0; e < KIN; ++e) {
                const int idx = in_idx[n*KIN + e];
                eins[wave][e][lane] = edges[(size_t)idx * D + lane];
            }
            // wave-private buffer: in-wave DS ordering suffices, no __syncthreads
            float denom = 0.f;
            #pragma unroll
            for (int e = 0; e < KIN; ++e) denom += (float)in_mask[n*KIN + e];
            denom = fmaxf(denom, 1.f);
            const float mk_k = (float)in_mask[n*KIN + kk8];
            const float mk_q = (float)in_mask[n*KIN + q];

            float s = 0.f;
            #pragma unroll
            for (int d4 = 0; d4 < D; d4 += 4) {
                const float4 a = *(const float4*)&eins[wave][q][d4];
                const float4 b = *(const float4*)&eins[wave][kk8][d4];
                s += a.x*b.x + a.y*b.y + a.z*b.z + a.w*b.w;
            }
            s *= 0.125f;
            if (mk_k == 0.f) s = -1e9f;

            float mx = s;
            #pragma unroll
            for (int off = 1; off < 8; off <<= 1) mx = fmaxf(mx, __shfl_xor(mx, off));
            const float ex = __expf(s - mx);
            float sum = ex;
            #pragma unroll
            for (int off = 1; off < 8; off <<= 1) sum += __shfl_xor(sum, off);

            float wk = mk_q * (ex / sum);
            #pragma unroll
            for (int off = 8; off < 64; off <<= 1) wk += __shfl_xor(wk, off);

            float p = 0.f;
            #pragma unroll
            for (int j = 0; j < KIN; ++j) p += __shfl(wk, j) * eins[wave][j][lane];
            p /= denom;
            const unsigned short pb = f2bf(p);

            #pragma unroll
            for (int j = 0; j < KOUT; ++j) {
                const int oi = out_idx[n*KOUT + j];
                xbuf[nl*KOUT + j][lane]     = f2bf(edges[(size_t)oi * D + lane]);
                xbuf[nl*KOUT + j][D + lane] = pb;
            }
            if (lane < KOUT) omaskf[nl*KOUT + lane] = (float)out_mask[n*KOUT + lane];
        }
    }
    __syncthreads();

    // ---------------- Phase 2: two 64x128x128 bf16-MFMA layers ----------------
    // wave -> 32 rows x 64 cols quadrant: 2 row-tiles x 4 col-tiles of 16x16
    const int rowbase = (wave >> 1) * 32;
    const int colbase = (wave & 1) * 64;
    const int l15  = lane & 15;
    const int kofs = (lane >> 4) * 8;
    const int rrow = (lane >> 4) * 4;      // D-fragment row group

    #pragma unroll
    for (int layer = 0; layer < 2; ++layer) {
        const unsigned short* __restrict__ Wl = Wbf + layer * (H*H);
        const float* __restrict__ bl = layer ? b1 : b0;

        f32x4 acc[2][4];
        #pragma unroll
        for (int ct = 0; ct < 4; ++ct) {
            const float bv = bl[colbase + ct*16 + l15];
            #pragma unroll
            for (int r = 0; r < 2; ++r) acc[r][ct] = (f32x4){bv, bv, bv, bv};
        }

        #pragma unroll
        for (int ks = 0; ks < 4; ++ks) {
            short8v bf[4];
            #pragma unroll
            for (int ct = 0; ct < 4; ++ct)
                bf[ct] = *(const short8v*)&Wl[(size_t)(colbase + ct*16 + l15) * H + ks*32 + kofs];
            #pragma unroll
            for (int r = 0; r < 2; ++r) {
                const short8v a = *(const short8v*)&xbuf[rowbase + r*16 + l15][ks*32 + kofs];
                #pragma unroll
                for (int ct = 0; ct < 4; ++ct)
                    acc[r][ct] = __builtin_amdgcn_mfma_f32_16x16x32_bf16(a, bf[ct], acc[r][ct], 0, 0, 0);
            }
        }
        __syncthreads();   // all A-reads of xbuf complete
        #pragma unroll
        for (int r = 0; r < 2; ++r)
            #pragma unroll
            for (int ct = 0; ct < 4; ++ct)
                #pragma unroll
                for (int j = 0; j < 4; ++j)
                    xbuf[rowbase + r*16 + rrow + j][colbase + ct*16 + l15] =
                        f2bf(fmaxf(acc[r][ct][j], 0.f));
        __syncthreads();   // h visible to all
    }

    // ---------------- epilogue: y = h1 . Wout + bout, masked ----------------
    {
        const int row = tid >> 2;          // 0..63
        const int kq  = tid & 3;           // k-quarter (32 each)
        float p = 0.f;
        #pragma unroll
        for (int m = 0; m < 4; ++m) {
            const int k0 = kq*32 + m*8;
            const short8v hv = *(const short8v*)&xbuf[row][k0];
            const float4 w0 = *(const float4*)&Wout[k0];
            const float4 w1 = *(const float4*)&Wout[k0 + 4];
            p += bf2f((unsigned short)hv[0]) * w0.x + bf2f((unsigned short)hv[1]) * w0.y
               + bf2f((unsigned short)hv[2]) * w0.z + bf2f((unsigned short)hv[3]) * w0.w
               + bf2f((unsigned short)hv[4]) * w1.x + bf2f((unsigned short)hv[5]) * w1.y
               + bf2f((unsigned short)hv[6]) * w1.z + bf2f((unsigned short)hv[7]) * w1.w;
        }
        p += __shfl_xor(p, 1);
        p += __shfl_xor(p, 2);
        if (kq == 0) {
            const long long grow = (long long)nodeBase * KOUT + row;
            if (grow < (long long)N * KOUT)
                out[grow] = (p + bout[0]) * omaskf[row];
        }
    }
}

extern "C" void kernel_launch(void* const* d_in, const int* in_sizes, int n_in,
                              void* d_out, int out_size, void* d_ws, size_t ws_size,
                              hipStream_t stream)
{
    const float* edges  = (const float*)d_in[0];
    const int* in_idx   = (const int*)d_in[1];
    const int* in_mask  = (const int*)d_in[2];
    const int* out_idx  = (const int*)d_in[3];
    const int* out_mask = (const int*)d_in[4];
    const float* W0   = (const float*)d_in[5];
    const float* b0   = (const float*)d_in[6];
    const float* W1   = (const float*)d_in[7];
    const float* b1   = (const float*)d_in[8];
    const float* Wout = (const float*)d_in[9];
    const float* bout = (const float*)d_in[10];
    float* out = (float*)d_out;
    unsigned short* Wbf = (unsigned short*)d_ws;   // 2*128*128 bf16 = 64 KB

    const int nNodes = in_sizes[1] / KIN;               // 200000
    convert_w_kernel<<<(2*H*H + 255) / 256, 256, 0, stream>>>(W0, W1, Wbf);
    const int grid = (nNodes + NPB - 1) / NPB;          // 12500
    encoder_kernel<<<grid, THREADS, 0, stream>>>(
        edges, in_idx, in_mask, out_idx, out_mask,
        b0, b1, Wout, bout, Wbf, out, nNodes);
}